// Round 14
// baseline (817.162 us; speedup 1.0000x reference)
//
#include <hip/hip_runtime.h>
#include <hip/hip_bf16.h>
#include <math.h>
#include <stdint.h>

#define TOK 32768
#define DIM 1024
#define NE 8
#define BMCAP (2 * TOK + NE * 256) /* 67584 row slots (segments padded to 256) */
#define CH 32768                   /* H chunk rows (128 m-tiles of 256) */
#define NCHUNK ((BMCAP + CH - 1) / CH) /* 3 */

// ctrl layout (ints): cnt[e] @ e*16 ; cursor[e] @ 128+e*16 ; seg_start[e] @ 256+e ; Mpad @ 264
#define C_CNT(e) ((e) * 16)
#define C_CUR(e) (128 + (e) * 16)
#define C_SEG(e) (256 + (e))
#define C_MPAD 264

typedef __attribute__((ext_vector_type(8))) short bf16x8;
typedef __attribute__((ext_vector_type(4))) float f32x4;
typedef unsigned short ushort_t;

__device__ __forceinline__ unsigned short f2b(float x) {
  union { float f; unsigned u; } v; v.f = x;
  unsigned r = v.u + 0x7fffu + ((v.u >> 16) & 1u);
  return (unsigned short)(r >> 16);
}

__device__ __forceinline__ void async16(void* lds, const void* g) {
  auto* lp = (__attribute__((address_space(3))) uint32_t*)lds;
  auto* gp = (__attribute__((address_space(1))) uint32_t*)(const_cast<void*>(g));
  __builtin_amdgcn_global_load_lds(gp, lp, 16, 0, 0);
}

// ---- router v3 (no atomics): FROZEN sequential fmaf chain ------------------
__global__ __launch_bounds__(256) void router_seq3(
    const float* __restrict__ tokens, const float* __restrict__ rw,
    int* __restrict__ topi, float* __restrict__ topv) {
  __shared__ float xs[2][32][132];
  __shared__ float wsh[2][8][132];
  __shared__ float sc[256];
  const int tid = threadIdx.x;
  const int e = tid & 7;
  const int tr = tid >> 3;
  const int t0 = blockIdx.x * 32;

  float4 lx0, lx1, lx2, lx3, lw;
  auto issue = [&](int c) {
    const int col = (tid & 31) * 4;
    lx0 = *(const float4*)&tokens[(size_t)(t0 + ((tid + 0) >> 5)) * DIM + c * 128 + col];
    lx1 = *(const float4*)&tokens[(size_t)(t0 + ((tid + 256) >> 5)) * DIM + c * 128 + col];
    lx2 = *(const float4*)&tokens[(size_t)(t0 + ((tid + 512) >> 5)) * DIM + c * 128 + col];
    lx3 = *(const float4*)&tokens[(size_t)(t0 + ((tid + 768) >> 5)) * DIM + c * 128 + col];
    lw  = *(const float4*)&rw[(size_t)(tid >> 5) * DIM + c * 128 + col];
  };
  auto commit = [&](int b) {
    const int col = (tid & 31) * 4;
    *(float4*)&xs[b][(tid + 0) >> 5][col] = lx0;
    *(float4*)&xs[b][(tid + 256) >> 5][col] = lx1;
    *(float4*)&xs[b][(tid + 512) >> 5][col] = lx2;
    *(float4*)&xs[b][(tid + 768) >> 5][col] = lx3;
    *(float4*)&wsh[b][tid >> 5][col] = lw;
  };

  issue(0);
  commit(0);
  __syncthreads();
  float s = 0.f;
  for (int c = 0; c < 8; c++) {
    const int b = c & 1;
    if (c + 1 < 8) issue(c + 1);
#pragma unroll
    for (int k4 = 0; k4 < 32; k4++) {
      const float4 xv = *(const float4*)&xs[b][tr][k4 * 4];
      const float4 wv = *(const float4*)&wsh[b][e][k4 * 4];
      s = fmaf(xv.x, wv.x, s);
      s = fmaf(xv.y, wv.y, s);
      s = fmaf(xv.z, wv.z, s);
      s = fmaf(xv.w, wv.w, s);
    }
    if (c + 1 < 8) commit(b ^ 1);
    __syncthreads();
  }
  sc[tid] = s;
  __syncthreads();
  if (e == 0) {
    float p[NE];
    float m = sc[tr * 8];
#pragma unroll
    for (int i = 1; i < NE; i++) m = fmaxf(m, sc[tr * 8 + i]);
    float sum = 0.f;
#pragma unroll
    for (int i = 0; i < NE; i++) {
      p[i] = expf(sc[tr * 8 + i] - m);
      sum += p[i];
    }
#pragma unroll
    for (int i = 0; i < NE; i++) p[i] = p[i] / sum;
    const int t = t0 + tr;
    int e0 = 0;
#pragma unroll
    for (int i = 1; i < NE; i++) if (p[i] > p[e0]) e0 = i;
    int e1 = (e0 == 0) ? 1 : 0;
#pragma unroll
    for (int i = 0; i < NE; i++) if (i != e0 && p[i] > p[e1]) e1 = i;
    topi[t * 2] = e0;     topv[t * 2] = p[e0];
    topi[t * 2 + 1] = e1; topv[t * 2 + 1] = p[e1];
  }
}

// ---- per-expert counts: LDS histogram -> padded global counters ------------
__global__ __launch_bounds__(256) void hist_kernel(const int* __restrict__ topi,
                                                   int* __restrict__ ctrl) {
  __shared__ int h[NE];
  const int tid = threadIdx.x;
  if (tid < NE) h[tid] = 0;
  __syncthreads();
  const int base = blockIdx.x * 512;
  atomicAdd(&h[topi[base + tid]], 1);
  atomicAdd(&h[topi[base + 256 + tid]], 1);
  __syncthreads();
  if (tid < NE) atomicAdd(&ctrl[C_CNT(tid)], h[tid]);
}

__global__ void prefix_kernel(int* ctrl) {
  if (threadIdx.x == 0 && blockIdx.x == 0) {
    int s = 0;
    for (int e = 0; e < NE; e++) {
      ctrl[C_SEG(e)] = s;
      ctrl[C_CUR(e)] = s;
      s += (ctrl[C_CNT(e)] + 255) & ~255; /* pad segments to 256 (BM) */
    }
    ctrl[C_MPAD] = s;
  }
}

__global__ __launch_bounds__(256) void init_rows(
    int* __restrict__ row_token, float* __restrict__ row_gate) {
  const int i = blockIdx.x * 256 + threadIdx.x;
  if (i < BMCAP) { row_token[i] = TOK; row_gate[i] = 0.f; }
}

// ---- assign v2: LDS-aggregated ranged reservation (8 atomics/block) --------
__global__ __launch_bounds__(256) void assign2(
    const int* __restrict__ topi, const float* __restrict__ topv,
    int* __restrict__ ctrl, int* __restrict__ row_token,
    float* __restrict__ row_gate) {
  __shared__ int h[NE];
  __shared__ int base[NE];
  const int tid = threadIdx.x;
  const int t = blockIdx.x * 256 + tid;
  if (tid < NE) h[tid] = 0;
  __syncthreads();
  const int e0 = topi[t * 2], e1 = topi[t * 2 + 1];
  const int o0 = atomicAdd(&h[e0], 1);
  const int o1 = atomicAdd(&h[e1], 1);
  __syncthreads();
  if (tid < NE) base[tid] = atomicAdd(&ctrl[C_CUR(tid)], h[tid]);
  __syncthreads();
  const int p0 = base[e0] + o0, p1 = base[e1] + o1;
  row_token[p0] = t; row_gate[p0] = topv[t * 2];
  row_token[p1] = t; row_gate[p1] = topv[t * 2 + 1];
}

// ---------------- tokens f32 -> bf16 ----------------------------------------
__global__ __launch_bounds__(256) void cast_tokens(
    const float* __restrict__ t, ushort_t* __restrict__ x16) {
  const size_t i = ((size_t)blockIdx.x * 256 + threadIdx.x) * 8;
  const float4 a = *(const float4*)(t + i);
  const float4 b = *(const float4*)(t + i + 4);
  bf16x8 h;
  h[0] = (short)f2b(a.x); h[1] = (short)f2b(a.y);
  h[2] = (short)f2b(a.z); h[3] = (short)f2b(a.w);
  h[4] = (short)f2b(b.x); h[5] = (short)f2b(b.y);
  h[6] = (short)f2b(b.z); h[7] = (short)f2b(b.w);
  *(bf16x8*)(x16 + i) = h;
}

// ---------------- weights: [E][K][N] f32 -> [E][N][K] bf16 ------------------
__global__ __launch_bounds__(256) void transpose_cast(
    const float* __restrict__ w, ushort_t* __restrict__ wT) {
  __shared__ float tile[64][65];
  const int e = blockIdx.z;
  const int n0 = blockIdx.x * 64, k0 = blockIdx.y * 64;
  const int tx = threadIdx.x & 63, ty = threadIdx.x >> 6;
  const float* src = w + ((size_t)e << 20);
  ushort_t* dst = wT + ((size_t)e << 20);
#pragma unroll
  for (int r = ty; r < 64; r += 4)
    tile[r][tx] = src[(size_t)(k0 + r) * DIM + n0 + tx];
  __syncthreads();
#pragma unroll
  for (int r = ty; r < 64; r += 4)
    dst[(size_t)(n0 + r) * DIM + k0 + tx] = f2b(tile[tx][r]);
}

// --- grouped GEMM: 256x256 tile, BK=64, 8 waves, dbuf, XOR-swizzled LDS -----
// Swizzle (both-sides, rule #21): LDS[row][colbyte] holds logical
// data[row][colbyte ^ ((row&7)<<4)]; staging pre-swizzles the GLOBAL source
// column, ds_read XORs the same involution. b128 reads spread 16 lanes over
// 8 distinct 16B slots -> ~conflict-free.
template <int PASS>
__global__ __launch_bounds__(512, 2) void dgemm(
    const ushort_t* __restrict__ Asrc, const ushort_t* __restrict__ Wt,
    const int* __restrict__ row_token, const float* __restrict__ row_gate,
    const int* __restrict__ ctrl, int cbase, ushort_t* __restrict__ Hout,
    float* __restrict__ out) {
  // 512 blocks, 64/XCD chunk (bijective), n-fastest within chunk
  const int l = (blockIdx.x & 7) * 64 + (blockIdx.x >> 3);
  const int mt = l >> 2, nt = l & 3;
  const int Mpad = ctrl[C_MPAD];
  const int m0 = cbase + mt * 256;
  if (m0 >= Mpad) return;
  const int m0loc = m0 - cbase;
  const int n0 = nt * 256;
  int e = 0;
#pragma unroll
  for (int i = 0; i < NE - 1; i++)
    if (m0 >= ctrl[C_SEG(i + 1)]) e = i + 1;
  const ushort_t* B = Wt + ((size_t)e << 20);

  __shared__ ushort_t As[2][256 * 64]; // 64 KB
  __shared__ ushort_t Bs[2][256 * 64]; // 64 KB
  const int tid = threadIdx.x;
  const int lane = tid & 63;
  const int wave = tid >> 6;
  const int wm = wave >> 2, wn = wave & 3; // 2M x 4N; per-wave 128x64 out
  const int lr = lane & 15;
  const int lk = (lane >> 4) << 3;
  const int sx = (lr & 7) << 3; // element-space read-swizzle XOR

  // staging: thread tid stages 4 rows of A and 4 of B per K-tile.
  // dest chunk = j*512 + tid -> row = j*64 + (tid>>3), dest colbyte=(tid&7)*16
  // source column pre-swizzled: ko = ((tid&7) ^ ((tid>>3)&7)) * 8 elements
  const int srow = tid >> 3;
  const int ko = (((tid & 7) ^ (srow & 7)) << 3);
  const ushort_t* asrc[4];
  const ushort_t* bsrc[4];
#pragma unroll
  for (int j = 0; j < 4; j++) {
    const int rA = j * 64 + srow;
    if (PASS == 0) {
      int tk = row_token[m0 + rA];
      if (tk >= TOK) tk = 0; /* pad rows: any valid row, result unused */
      asrc[j] = Asrc + (size_t)tk * DIM + ko;
    } else {
      asrc[j] = Asrc + (size_t)(m0loc + rA) * DIM + ko;
    }
    bsrc[j] = B + (size_t)(n0 + rA) * DIM + ko;
  }
  const int ldst = (tid & ~63) * 8; // wave-uniform element base (lane*16B added by HW)

  f32x4 acc[8][4] = {};

  auto stage = [&](int b, int k0) {
#pragma unroll
    for (int j = 0; j < 4; j++)
      async16(&As[b][j * 4096 + ldst], asrc[j] + k0);
#pragma unroll
    for (int j = 0; j < 4; j++)
      async16(&Bs[b][j * 4096 + ldst], bsrc[j] + k0);
  };
  auto compute = [&](int b) {
#pragma unroll
    for (int kk = 0; kk < 2; kk++) {
      const int kc = (kk * 32 + lk) ^ sx;
      bf16x8 a[8], bb[4];
#pragma unroll
      for (int i = 0; i < 8; i++)
        a[i] = *(const bf16x8*)&As[b][(wm * 128 + i * 16 + lr) * 64 + kc];
#pragma unroll
      for (int i = 0; i < 4; i++)
        bb[i] = *(const bf16x8*)&Bs[b][(wn * 64 + i * 16 + lr) * 64 + kc];
#pragma unroll
      for (int mi = 0; mi < 8; mi++)
#pragma unroll
        for (int ni = 0; ni < 4; ni++)
          acc[mi][ni] = __builtin_amdgcn_mfma_f32_16x16x32_bf16(
              a[mi], bb[ni], acc[mi][ni], 0, 0, 0);
    }
  };

  stage(0, 0);
  __syncthreads();
  int cur = 0;
#pragma unroll 1
  for (int t = 0; t < 15; t++) {
    stage(cur ^ 1, (t + 1) * 64); // fly during compute
    compute(cur);
    __syncthreads();
    cur ^= 1;
  }
  compute(cur);

  const int grow = (lane >> 4) << 2;
  if (PASS == 0) {
#pragma unroll
    for (int mi = 0; mi < 8; mi++) {
      const int rloc = m0loc + wm * 128 + mi * 16 + grow;
#pragma unroll
      for (int ni = 0; ni < 4; ni++) {
        const int col = n0 + wn * 64 + ni * 16 + lr;
#pragma unroll
        for (int r = 0; r < 4; r++) {
          const float x = acc[mi][ni][r];
          const float g = 0.5f * x * (1.f + erff(x * 0.70710678118654752f));
          Hout[(size_t)(rloc + r) * DIM + col] = f2b(g);
        }
      }
    }
  } else {
#pragma unroll
    for (int mi = 0; mi < 8; mi++) {
      const int rbase = m0 + wm * 128 + mi * 16 + grow;
#pragma unroll
      for (int r = 0; r < 4; r++) {
        const int rr = rbase + r;
        const int tok = row_token[rr];
        if (tok < TOK) {
          const float g = row_gate[rr];
          float* op = out + (size_t)tok * DIM + n0 + wn * 64 + lr;
#pragma unroll
          for (int ni = 0; ni < 4; ni++)
            atomicAdd(op + ni * 16, g * acc[mi][ni][r]);
        }
      }
    }
  }
}

extern "C" void kernel_launch(void* const* d_in, const int* in_sizes, int n_in,
                              void* d_out, int out_size, void* d_ws,
                              size_t ws_size, hipStream_t stream) {
  (void)in_sizes; (void)n_in; (void)ws_size;
  const float* tokens = (const float*)d_in[0];
  const float* rw = (const float*)d_in[1];
  const float* w1 = (const float*)d_in[2];
  const float* w2 = (const float*)d_in[3];
  float* out = (float*)d_out;

  char* ws = (char*)d_ws;
  size_t off = 0;
  auto alloc = [&](size_t b) {
    size_t o = off;
    off += (b + 255) & ~(size_t)255;
    return o;
  };
  int* ctrl = (int*)(ws + alloc(2048));
  int* topi = (int*)(ws + alloc((size_t)TOK * 2 * 4));
  float* topv = (float*)(ws + alloc((size_t)TOK * 2 * 4));
  int* row_token = (int*)(ws + alloc((size_t)BMCAP * 4));
  float* row_gate = (float*)(ws + alloc((size_t)BMCAP * 4));
  ushort_t* X16 = (ushort_t*)(ws + alloc((size_t)TOK * DIM * 2));
  ushort_t* w1T = (ushort_t*)(ws + alloc((size_t)NE * DIM * DIM * 2));
  ushort_t* w2T = (ushort_t*)(ws + alloc((size_t)NE * DIM * DIM * 2));
  ushort_t* H = (ushort_t*)(ws + alloc((size_t)CH * DIM * 2));

  hipMemsetAsync(ctrl, 0, 2048, stream);
  router_seq3<<<TOK / 32, 256, 0, stream>>>(tokens, rw, topi, topv);
  hist_kernel<<<TOK * 2 / 512, 256, 0, stream>>>(topi, ctrl);
  prefix_kernel<<<1, 64, 0, stream>>>(ctrl);
  init_rows<<<(BMCAP + 255) / 256, 256, 0, stream>>>(row_token, row_gate);
  assign2<<<TOK / 256, 256, 0, stream>>>(topi, topv, ctrl, row_token,
                                         row_gate);
  cast_tokens<<<TOK * DIM / 8 / 256, 256, 0, stream>>>(tokens, X16);
  dim3 tg(16, 16, 8);
  transpose_cast<<<tg, 256, 0, stream>>>(w1, w1T);
  transpose_cast<<<tg, 256, 0, stream>>>(w2, w2T);
  hipMemsetAsync(out, 0, (size_t)out_size * 4, stream);
  for (int c = 0; c < NCHUNK; c++) {
    dgemm<0><<<512, 512, 0, stream>>>(X16, w1T, row_token, row_gate, ctrl,
                                      c * CH, H, out);
    dgemm<1><<<512, 512, 0, stream>>>(H, w2T, row_token, row_gate, ctrl,
                                      c * CH, H, out);
  }
}

// Round 15
// 715.434 us; speedup vs baseline: 1.1422x; 1.1422x over previous
//
#include <hip/hip_runtime.h>
#include <hip/hip_bf16.h>
#include <math.h>
#include <stdint.h>

#define TOK 32768
#define DIM 1024
#define NE 8
#define NSEG 16                       /* (k, expert) segments */
#define BMCAP (2 * TOK + NSEG * 256)  /* 69632 row slots */
#define RCAP (TOK + NE * 256)         /* 34816 rows per k-region cap */

// ctrl ints: cnt[s]@s*16 (s<16) ; cur[s]@256+s*16 ; seg[s]@512+s (s<=16)
#define C_CNT(s) ((s) * 16)
#define C_CUR(s) (256 + (s) * 16)
#define C_SEG(s) (512 + (s))

typedef __attribute__((ext_vector_type(8))) short bf16x8;
typedef __attribute__((ext_vector_type(4))) float f32x4;
typedef unsigned short ushort_t;

__device__ __forceinline__ unsigned short f2b(float x) {
  union { float f; unsigned u; } v; v.f = x;
  unsigned r = v.u + 0x7fffu + ((v.u >> 16) & 1u);
  return (unsigned short)(r >> 16);
}

__device__ __forceinline__ void async16(void* lds, const void* g) {
  auto* lp = (__attribute__((address_space(3))) uint32_t*)lds;
  auto* gp = (__attribute__((address_space(1))) uint32_t*)(const_cast<void*>(g));
  __builtin_amdgcn_global_load_lds(gp, lp, 16, 0, 0);
}

// ---- router v3 (no atomics): FROZEN sequential fmaf chain ------------------
__global__ __launch_bounds__(256) void router_seq3(
    const float* __restrict__ tokens, const float* __restrict__ rw,
    int* __restrict__ topi, float* __restrict__ topv) {
  __shared__ float xs[2][32][132];
  __shared__ float wsh[2][8][132];
  __shared__ float sc[256];
  const int tid = threadIdx.x;
  const int e = tid & 7;
  const int tr = tid >> 3;
  const int t0 = blockIdx.x * 32;

  float4 lx0, lx1, lx2, lx3, lw;
  auto issue = [&](int c) {
    const int col = (tid & 31) * 4;
    lx0 = *(const float4*)&tokens[(size_t)(t0 + ((tid + 0) >> 5)) * DIM + c * 128 + col];
    lx1 = *(const float4*)&tokens[(size_t)(t0 + ((tid + 256) >> 5)) * DIM + c * 128 + col];
    lx2 = *(const float4*)&tokens[(size_t)(t0 + ((tid + 512) >> 5)) * DIM + c * 128 + col];
    lx3 = *(const float4*)&tokens[(size_t)(t0 + ((tid + 768) >> 5)) * DIM + c * 128 + col];
    lw  = *(const float4*)&rw[(size_t)(tid >> 5) * DIM + c * 128 + col];
  };
  auto commit = [&](int b) {
    const int col = (tid & 31) * 4;
    *(float4*)&xs[b][(tid + 0) >> 5][col] = lx0;
    *(float4*)&xs[b][(tid + 256) >> 5][col] = lx1;
    *(float4*)&xs[b][(tid + 512) >> 5][col] = lx2;
    *(float4*)&xs[b][(tid + 768) >> 5][col] = lx3;
    *(float4*)&wsh[b][tid >> 5][col] = lw;
  };

  issue(0);
  commit(0);
  __syncthreads();
  float s = 0.f;
  for (int c = 0; c < 8; c++) {
    const int b = c & 1;
    if (c + 1 < 8) issue(c + 1);
#pragma unroll
    for (int k4 = 0; k4 < 32; k4++) {
      const float4 xv = *(const float4*)&xs[b][tr][k4 * 4];
      const float4 wv = *(const float4*)&wsh[b][e][k4 * 4];
      s = fmaf(xv.x, wv.x, s);
      s = fmaf(xv.y, wv.y, s);
      s = fmaf(xv.z, wv.z, s);
      s = fmaf(xv.w, wv.w, s);
    }
    if (c + 1 < 8) commit(b ^ 1);
    __syncthreads();
  }
  sc[tid] = s;
  __syncthreads();
  if (e == 0) {
    float p[NE];
    float m = sc[tr * 8];
#pragma unroll
    for (int i = 1; i < NE; i++) m = fmaxf(m, sc[tr * 8 + i]);
    float sum = 0.f;
#pragma unroll
    for (int i = 0; i < NE; i++) {
      p[i] = expf(sc[tr * 8 + i] - m);
      sum += p[i];
    }
#pragma unroll
    for (int i = 0; i < NE; i++) p[i] = p[i] / sum;
    const int t = t0 + tr;
    int e0 = 0;
#pragma unroll
    for (int i = 1; i < NE; i++) if (p[i] > p[e0]) e0 = i;
    int e1 = (e0 == 0) ? 1 : 0;
#pragma unroll
    for (int i = 0; i < NE; i++) if (i != e0 && p[i] > p[e1]) e1 = i;
    topi[t * 2] = e0;     topv[t * 2] = p[e0];
    topi[t * 2 + 1] = e1; topv[t * 2 + 1] = p[e1];
  }
}

// ---- per-(k,expert) counts: LDS histogram -> padded global counters --------
__global__ __launch_bounds__(256) void hist_kernel(const int* __restrict__ topi,
                                                   int* __restrict__ ctrl) {
  __shared__ int h[NSEG];
  const int tid = threadIdx.x;
  if (tid < NSEG) h[tid] = 0;
  __syncthreads();
  const int t = blockIdx.x * 256 + tid;
  atomicAdd(&h[topi[t * 2]], 1);
  atomicAdd(&h[8 + topi[t * 2 + 1]], 1);
  __syncthreads();
  if (tid < NSEG) atomicAdd(&ctrl[C_CNT(tid)], h[tid]);
}

__global__ void prefix_kernel(int* ctrl) {
  if (threadIdx.x == 0 && blockIdx.x == 0) {
    int s = 0;
    for (int g = 0; g < NSEG; g++) {
      ctrl[C_SEG(g)] = s;
      ctrl[C_CUR(g)] = s;
      s += (ctrl[C_CNT(g)] + 255) & ~255; /* pad segments to 256 (BM) */
    }
    ctrl[C_SEG(NSEG)] = s;
  }
}

__global__ __launch_bounds__(256) void init_rows(
    int* __restrict__ row_token, float* __restrict__ row_gate) {
  const int i = blockIdx.x * 256 + threadIdx.x;
  if (i < BMCAP) { row_token[i] = TOK; row_gate[i] = 0.f; }
}

// ---- assign: LDS-aggregated ranged reservation (16 atomics/block) ----------
__global__ __launch_bounds__(256) void assign2(
    const int* __restrict__ topi, const float* __restrict__ topv,
    int* __restrict__ ctrl, int* __restrict__ row_token,
    float* __restrict__ row_gate) {
  __shared__ int h[NSEG];
  __shared__ int base[NSEG];
  const int tid = threadIdx.x;
  const int t = blockIdx.x * 256 + tid;
  if (tid < NSEG) h[tid] = 0;
  __syncthreads();
  const int s0 = topi[t * 2], s1 = 8 + topi[t * 2 + 1];
  const int o0 = atomicAdd(&h[s0], 1);
  const int o1 = atomicAdd(&h[s1], 1);
  __syncthreads();
  if (tid < NSEG) base[tid] = atomicAdd(&ctrl[C_CUR(tid)], h[tid]);
  __syncthreads();
  const int p0 = base[s0] + o0, p1 = base[s1] + o1;
  row_token[p0] = t; row_gate[p0] = topv[t * 2];
  row_token[p1] = t; row_gate[p1] = topv[t * 2 + 1];
}

// ---------------- tokens f32 -> bf16 ----------------------------------------
__global__ __launch_bounds__(256) void cast_tokens(
    const float* __restrict__ t, ushort_t* __restrict__ x16) {
  const size_t i = ((size_t)blockIdx.x * 256 + threadIdx.x) * 8;
  const float4 a = *(const float4*)(t + i);
  const float4 b = *(const float4*)(t + i + 4);
  bf16x8 h;
  h[0] = (short)f2b(a.x); h[1] = (short)f2b(a.y);
  h[2] = (short)f2b(a.z); h[3] = (short)f2b(a.w);
  h[4] = (short)f2b(b.x); h[5] = (short)f2b(b.y);
  h[6] = (short)f2b(b.z); h[7] = (short)f2b(b.w);
  *(bf16x8*)(x16 + i) = h;
}

// ---------------- weights: [E][K][N] f32 -> [E][N][K] bf16 ------------------
__global__ __launch_bounds__(256) void transpose_cast(
    const float* __restrict__ w, ushort_t* __restrict__ wT) {
  __shared__ float tile[64][65];
  const int e = blockIdx.z;
  const int n0 = blockIdx.x * 64, k0 = blockIdx.y * 64;
  const int tx = threadIdx.x & 63, ty = threadIdx.x >> 6;
  const float* src = w + ((size_t)e << 20);
  ushort_t* dst = wT + ((size_t)e << 20);
#pragma unroll
  for (int r = ty; r < 64; r += 4)
    tile[r][tx] = src[(size_t)(k0 + r) * DIM + n0 + tx];
  __syncthreads();
#pragma unroll
  for (int r = ty; r < 64; r += 4)
    dst[(size_t)(n0 + r) * DIM + k0 + tx] = f2b(tile[tx][r]);
}

// --- grouped GEMM: 256x256, BK=64, 8 waves, dbuf+swizzle K-loop (r14) -------
// NEW: LDS-transpose epilogue -> coalesced wide stores; no atomics.
// PASS 0:        H[rloc,:] = gelu(A @ B^T)         (bf16x8 stores)
// PASS 1,ADD=0:  out[tok,:] = g * (H @ B^T)        (float4 stores, k=0 region)
// PASS 1,ADD=1:  out[tok,:] += g * (H @ B^T)       (float4 RMW, k=1 region)
template <int PASS, int ADD>
__global__ __launch_bounds__(512, 2) void dgemm(
    const ushort_t* __restrict__ Asrc, const ushort_t* __restrict__ Wt,
    const int* __restrict__ row_token, const float* __restrict__ row_gate,
    const int* __restrict__ ctrl, int kreg, ushort_t* __restrict__ Hout,
    float* __restrict__ out) {
  const int l = (blockIdx.x & 7) * 68 + (blockIdx.x >> 3); // 544 = 8 x 68
  const int mt = l >> 2, nt = l & 3;
  const int rbase0 = ctrl[C_SEG(kreg * 8)];
  const int rend = ctrl[C_SEG(kreg * 8 + 8)];
  const int m0 = rbase0 + mt * 256;
  if (m0 >= rend) return;
  const int m0loc = m0 - rbase0;
  const int n0 = nt * 256;
  int e = 0;
#pragma unroll
  for (int i = 0; i < NE - 1; i++)
    if (m0 >= ctrl[C_SEG(kreg * 8 + i + 1)]) e = i + 1;
  const ushort_t* B = Wt + ((size_t)e << 20);

  __shared__ __align__(16) char smem[131072];
  ushort_t (*As)[16384] = (ushort_t(*)[16384])smem;            // 2 x 32 KB
  ushort_t (*Bs)[16384] = (ushort_t(*)[16384])(smem + 65536);  // 2 x 32 KB
  float* scratch = (float*)smem; // epilogue: per-wave 4096 f32 (16 KB)

  const int tid = threadIdx.x;
  const int lane = tid & 63;
  const int wave = tid >> 6;
  const int wm = wave >> 2, wn = wave & 3; // per-wave 128x64 output
  const int lr = lane & 15;
  const int lk = (lane >> 4) << 3;
  const int sx = (lr & 7) << 3;

  const int srow = tid >> 3;
  const int ko = (((tid & 7) ^ (srow & 7)) << 3); // pre-swizzled source col
  const ushort_t* asrc[4];
  const ushort_t* bsrc[4];
#pragma unroll
  for (int j = 0; j < 4; j++) {
    const int rA = j * 64 + srow;
    if (PASS == 0) {
      int tk = row_token[m0 + rA];
      if (tk >= TOK) tk = 0;
      asrc[j] = Asrc + (size_t)tk * DIM + ko;
    } else {
      asrc[j] = Asrc + (size_t)(m0loc + rA) * DIM + ko;
    }
    bsrc[j] = B + (size_t)(n0 + rA) * DIM + ko;
  }
  const int ldst = (tid & ~63) * 8;

  f32x4 acc[8][4] = {};

  auto stage = [&](int b, int k0) {
#pragma unroll
    for (int j = 0; j < 4; j++) async16(&As[b][j * 4096 + ldst], asrc[j] + k0);
#pragma unroll
    for (int j = 0; j < 4; j++) async16(&Bs[b][j * 4096 + ldst], bsrc[j] + k0);
  };
  auto compute = [&](int b) {
#pragma unroll
    for (int kk = 0; kk < 2; kk++) {
      const int kc = (kk * 32 + lk) ^ sx;
      bf16x8 a[8], bb[4];
#pragma unroll
      for (int i = 0; i < 8; i++)
        a[i] = *(const bf16x8*)&As[b][(wm * 128 + i * 16 + lr) * 64 + kc];
#pragma unroll
      for (int i = 0; i < 4; i++)
        bb[i] = *(const bf16x8*)&Bs[b][(wn * 64 + i * 16 + lr) * 64 + kc];
#pragma unroll
      for (int mi = 0; mi < 8; mi++)
#pragma unroll
        for (int ni = 0; ni < 4; ni++)
          acc[mi][ni] = __builtin_amdgcn_mfma_f32_16x16x32_bf16(
              a[mi], bb[ni], acc[mi][ni], 0, 0, 0);
    }
  };

  stage(0, 0);
  __syncthreads();
  int cur = 0;
#pragma unroll 1
  for (int t = 0; t < 15; t++) {
    stage(cur ^ 1, (t + 1) * 64);
    compute(cur);
    __syncthreads();
    cur ^= 1;
  }
  compute(cur);
  __syncthreads(); // all waves done with As/Bs before scratch reuse

  // ---- LDS-transpose epilogue: per-wave exclusive 64x64 f32 window --------
  // physical col = logical col ^ (((lrow>>2)&3)<<4)  (write-side bank spread)
  const int grow = (lane >> 4) << 2;
  float* sw = scratch + wave * 4096;
#pragma unroll
  for (int half = 0; half < 2; half++) {
#pragma unroll
    for (int mi2 = 0; mi2 < 4; mi2++) {
      const int mi = half * 4 + mi2;
#pragma unroll
      for (int ni = 0; ni < 4; ni++) {
#pragma unroll
        for (int r = 0; r < 4; r++) {
          const int lrow = mi2 * 16 + grow + r;
          const int lcol = (ni * 16 + lr) ^ (((lrow >> 2) & 3) << 4);
          sw[lrow * 64 + lcol] = acc[mi][ni][r];
        }
      }
    }
    // wave-internal ds_write -> ds_read ordering handled by compiler waits
    if (PASS == 0) {
#pragma unroll
      for (int i = 0; i < 8; i++) {
        const int lrow = i * 8 + (lane >> 3);
        const int q = ((lrow >> 2) & 3) << 4;
        const int c0 = (lane & 7) * 8;
        const f32x4 v0 = *(const f32x4*)&sw[lrow * 64 + (c0 ^ q)];
        const f32x4 v1 = *(const f32x4*)&sw[lrow * 64 + (c0 ^ q) + 4];
        bf16x8 h;
#pragma unroll
        for (int j = 0; j < 4; j++) {
          const float x = v0[j];
          const float g = 0.5f * x * (1.f + erff(x * 0.70710678118654752f));
          h[j] = (short)f2b(g);
        }
#pragma unroll
        for (int j = 0; j < 4; j++) {
          const float x = v1[j];
          const float g = 0.5f * x * (1.f + erff(x * 0.70710678118654752f));
          h[4 + j] = (short)f2b(g);
        }
        const int rloc = m0loc + wm * 128 + half * 64 + lrow;
        *(bf16x8*)&Hout[(size_t)rloc * DIM + n0 + wn * 64 + c0] = h;
      }
    } else {
#pragma unroll
      for (int i = 0; i < 16; i++) {
        const int lrow = i * 4 + (lane >> 4);
        const int q = ((lrow >> 2) & 3) << 4;
        const int c0 = (lane & 15) * 4;
        const f32x4 v = *(const f32x4*)&sw[lrow * 64 + (c0 ^ q)];
        const int rr = m0 + wm * 128 + half * 64 + lrow;
        const int tok = row_token[rr];
        if (tok < TOK) {
          const float g = row_gate[rr];
          float* op = out + (size_t)tok * DIM + n0 + wn * 64 + c0;
          f32x4 res;
          if (ADD) {
            const f32x4 old = *(const f32x4*)op;
#pragma unroll
            for (int j = 0; j < 4; j++) res[j] = old[j] + g * v[j];
          } else {
#pragma unroll
            for (int j = 0; j < 4; j++) res[j] = g * v[j];
          }
          *(f32x4*)op = res;
        }
      }
    }
  }
}

extern "C" void kernel_launch(void* const* d_in, const int* in_sizes, int n_in,
                              void* d_out, int out_size, void* d_ws,
                              size_t ws_size, hipStream_t stream) {
  (void)in_sizes; (void)n_in; (void)ws_size; (void)out_size;
  const float* tokens = (const float*)d_in[0];
  const float* rw = (const float*)d_in[1];
  const float* w1 = (const float*)d_in[2];
  const float* w2 = (const float*)d_in[3];
  float* out = (float*)d_out;

  char* ws = (char*)d_ws;
  size_t off = 0;
  auto alloc = [&](size_t b) {
    size_t o = off;
    off += (b + 255) & ~(size_t)255;
    return o;
  };
  int* ctrl = (int*)(ws + alloc(4096));
  int* topi = (int*)(ws + alloc((size_t)TOK * 2 * 4));
  float* topv = (float*)(ws + alloc((size_t)TOK * 2 * 4));
  int* row_token = (int*)(ws + alloc((size_t)BMCAP * 4));
  float* row_gate = (float*)(ws + alloc((size_t)BMCAP * 4));
  ushort_t* X16 = (ushort_t*)(ws + alloc((size_t)TOK * DIM * 2));
  ushort_t* w1T = (ushort_t*)(ws + alloc((size_t)NE * DIM * DIM * 2));
  ushort_t* w2T = (ushort_t*)(ws + alloc((size_t)NE * DIM * DIM * 2));
  ushort_t* H = (ushort_t*)(ws + alloc((size_t)RCAP * DIM * 2));

  hipMemsetAsync(ctrl, 0, 4096, stream);
  router_seq3<<<TOK / 32, 256, 0, stream>>>(tokens, rw, topi, topv);
  hist_kernel<<<TOK / 256, 256, 0, stream>>>(topi, ctrl);
  prefix_kernel<<<1, 64, 0, stream>>>(ctrl);
  init_rows<<<BMCAP / 256, 256, 0, stream>>>(row_token, row_gate);
  assign2<<<TOK / 256, 256, 0, stream>>>(topi, topv, ctrl, row_token,
                                         row_gate);
  cast_tokens<<<TOK * DIM / 8 / 256, 256, 0, stream>>>(tokens, X16);
  dim3 tg(16, 16, 8);
  transpose_cast<<<tg, 256, 0, stream>>>(w1, w1T);
  transpose_cast<<<tg, 256, 0, stream>>>(w2, w2T);
  // no out memset: k=0 pass-1 stores every token row
  dgemm<0, 0><<<544, 512, 0, stream>>>(X16, w1T, row_token, row_gate, ctrl, 0,
                                       H, out);
  dgemm<1, 0><<<544, 512, 0, stream>>>(H, w2T, row_token, row_gate, ctrl, 0, H,
                                       out);
  dgemm<0, 0><<<544, 512, 0, stream>>>(X16, w1T, row_token, row_gate, ctrl, 1,
                                       H, out);
  dgemm<1, 1><<<544, 512, 0, stream>>>(H, w2T, row_token, row_gate, ctrl, 1, H,
                                       out);
}